// Round 19
// baseline (48.852 us; speedup 1.0000x reference)
//
#include <hip/hip_runtime.h>

// ---- f64 DCT magnitudes (0.5*cos(m*pi/16)); f32 casts match np.asarray(D,f32).
#define C0 0.35355339059327373
#define C1 0.49039264020161522
#define C2 0.46193976625564337
#define C3 0.41573480615127262
#define C5 0.27778511650980109
#define C6 0.19134171618254489
#define C7 0.09754516100806413

#define F0 ((float)C0)
#define F1 ((float)C1)
#define F2 ((float)C2)
#define F3 ((float)C3)
#define F5 ((float)C5)
#define F6 ((float)C6)
#define F7 ((float)C7)

// ---- exact-f32 scalar helpers (boundary-critical paths).
__device__ __forceinline__ float mulf(float a, float b) {
#pragma clang fp contract(off)
    return a * b;
}
__device__ __forceinline__ float addf(float a, float b) {
#pragma clang fp contract(off)
    return a + b;
}
__device__ __forceinline__ float subf(float a, float b) {
#pragma clang fp contract(off)
    return a - b;
}
__device__ __forceinline__ float divf(float a, float b) {
#pragma clang fp contract(off)
    return a / b;
}

// ---- forward DCT-II butterfly: m[i] <- sum_n D[i][n]*m[n]. Accumulation
// order differs from ref's chain by <= ~10 ulps -> covered by the hedge band.
__device__ __forceinline__ void fwd8(float m[8]) {
    const float e0 = m[0] + m[7], e1 = m[1] + m[6], e2 = m[2] + m[5], e3 = m[3] + m[4];
    const float o0 = m[0] - m[7], o1 = m[1] - m[6], o2 = m[2] - m[5], o3 = m[3] - m[4];
    m[0] = F0 * (e0 + e1 + e2 + e3);
    m[4] = F0 * (e0 - e1 - e2 + e3);
    m[2] = F2*e0 + F6*e1 - F6*e2 - F2*e3;
    m[6] = F6*e0 - F2*e1 + F2*e2 - F6*e3;
    m[1] = F1*o0 + F3*o1 + F5*o2 + F7*o3;
    m[3] = F3*o0 - F7*o1 - F1*o2 - F5*o3;
    m[5] = F5*o0 - F1*o1 + F7*o2 + F3*o3;
    m[7] = F7*o0 - F5*o1 + F3*o2 - F1*o3;
}

// ---- fast f32 IDCT butterfly: out[n] = sum_u D[u][n]*in[u]. Precision
// non-critical (affects only +-1-level final pixel rounding = 0.0078).
__device__ __forceinline__ void inv8f(float m[8]) {
    const float a0 = F0*m[0] + F2*m[2] + F0*m[4] + F6*m[6];
    const float a1 = F0*m[0] + F6*m[2] - F0*m[4] - F2*m[6];
    const float a2 = F0*m[0] - F6*m[2] - F0*m[4] + F2*m[6];
    const float a3 = F0*m[0] - F2*m[2] + F0*m[4] - F6*m[6];
    const float o0 = F1*m[1] + F3*m[3] + F5*m[5] + F7*m[7];
    const float o1 = F3*m[1] - F7*m[3] - F1*m[5] - F5*m[7];
    const float o2 = F5*m[1] - F1*m[3] + F7*m[5] + F3*m[7];
    const float o3 = F7*m[1] - F5*m[3] + F3*m[5] - F1*m[7];
    m[0] = a0 + o0; m[7] = a0 - o0;
    m[1] = a1 + o1; m[6] = a1 - o1;
    m[2] = a2 + o2; m[5] = a2 - o2;
    m[3] = a3 + o3; m[4] = a3 - o3;
}

__device__ __forceinline__ float dpp_xor8(float x) {
    // DPP row_ror:8 on 16-lane rows == lane ^ 8 (builtin: compiler-managed hazards).
    return __builtin_bit_cast(float,
        __builtin_amdgcn_mov_dpp(__builtin_bit_cast(int, x), 0x128, 0xf, 0xf, true));
}

// Hazard-hardened permlane swaps: inline-asm opcodes are invisible to LLVM's
// hazard recognizer, so the required VALU<->permlane wait states are embedded
// (s_nop 1 = 2 wait cycles on each side) making them schedule-independent.
#define SWAP16(a, b) \
    asm volatile("s_nop 1\n\tv_permlane16_swap_b32 %0, %1\n\ts_nop 1" \
                 : "+v"(a), "+v"(b))
#define SWAP32(a, b) \
    asm volatile("s_nop 1\n\tv_permlane32_swap_b32 %0, %1\n\ts_nop 1" \
                 : "+v"(a), "+v"(b))

// 8x8 transpose of SIX pipelines (2 sets x 3 channels), stage-interleaved.
__device__ __forceinline__ void transpose6(float m[6][8], int g) {
    const bool up1 = (g & 1) != 0;
#pragma unroll
    for (int c = 0; c < 6; ++c) {
#pragma unroll
        for (int j = 0; j < 8; j += 2) {
            const int jj = j | 1;
            const float yj  = dpp_xor8(m[c][j]);
            const float yjj = dpp_xor8(m[c][jj]);
            m[c][j]  = up1 ? yjj : m[c][j];
            m[c][jj] = up1 ? m[c][jj] : yj;
        }
    }
#pragma unroll
    for (int c = 0; c < 6; ++c) {
#pragma unroll
        for (int j = 0; j < 8; ++j) {
            if ((j & 2) == 0) {
                const int jj = j | 2;
                SWAP16(m[c][j], m[c][jj]);
            }
        }
    }
#pragma unroll
    for (int c = 0; c < 6; ++c) {
#pragma unroll
        for (int j = 0; j < 4; ++j) {
            const int jj = j | 4;
            SWAP32(m[c][j], m[c][jj]);
        }
    }
}

// Exact f32 rgb->ycbcr (literal numpy op order, rintf = RNE = np.round), then
// center by -128 (Sterbenz-exact). Must be bit-exact: feeds quant boundaries.
__device__ __forceinline__ void color_in(const float* __restrict__ p, size_t plane,
                                         float T0[8], float T1[8], float T2[8]) {
    const float4 r0 = *reinterpret_cast<const float4*>(p);
    const float4 r1 = *reinterpret_cast<const float4*>(p + 4);
    const float4 g0 = *reinterpret_cast<const float4*>(p + plane);
    const float4 g1 = *reinterpret_cast<const float4*>(p + plane + 4);
    const float4 b0 = *reinterpret_cast<const float4*>(p + 2 * plane);
    const float4 b1 = *reinterpret_cast<const float4*>(p + 2 * plane + 4);
    const float Rf[8] = {r0.x, r0.y, r0.z, r0.w, r1.x, r1.y, r1.z, r1.w};
    const float Gf[8] = {g0.x, g0.y, g0.z, g0.w, g1.x, g1.y, g1.z, g1.w};
    const float Bf[8] = {b0.x, b0.y, b0.z, b0.w, b1.x, b1.y, b1.z, b1.w};
#pragma unroll
    for (int j = 0; j < 8; ++j) {
        const float xr = mulf(addf(mulf(Rf[j], 0.5f), 0.5f), 255.0f);
        const float xg = mulf(addf(mulf(Gf[j], 0.5f), 0.5f), 255.0f);
        const float xb = mulf(addf(mulf(Bf[j], 0.5f), 0.5f), 255.0f);
        const float Yi  = rintf(addf(addf(addf(mulf((float)0.256788, xr), mulf((float)0.504129, xg)),
                                          mulf((float)0.0979059, xb)), 16.0f));
        const float Cbi = rintf(addf(subf(subf(128.0f, mulf((float)0.148224, xr)),
                                          mulf((float)0.290992, xg)), mulf((float)0.439216, xb)));
        const float Cri = rintf(subf(subf(addf(128.0f, mulf((float)0.439216, xr)),
                                          mulf((float)0.367788, xg)), mulf((float)0.0714275, xb)));
        T0[j] = subf(Yi,  128.0f);
        T1[j] = subf(Cbi, 128.0f);
        T2[j] = subf(Cri, 128.0f);
    }
}

// Fast final color stage + store (continuous path: 1e-7-level deviation ok).
__device__ __forceinline__ void color_out(float* __restrict__ o, size_t plane,
                                          const float T0[8], const float T1[8],
                                          const float T2[8]) {
    float fr[8], fg[8], fb[8];
    const float S = 2.0f / 255.0f;
#pragma unroll
    for (int j = 0; j < 8; ++j) {
        const float y  = T0[j] + 112.0f;            // (+128) - 16
        const float cb = T1[j];                      // (+128) - 128
        const float cr = T2[j];
        const float Rv = rintf(__builtin_fmaf(1.16438f, y,
                               __builtin_fmaf(1.59603f, cr, 3.01124e-07f * cb)));
        const float Gv = rintf(__builtin_fmaf(1.16438f, y,
                               -__builtin_fmaf(0.391763f, cb, 0.812968f * cr)));
        const float Bv = rintf(__builtin_fmaf(1.16438f, y,
                               __builtin_fmaf(2.01723f, cb, 3.05426e-06f * cr)));
        fr[j] = __builtin_fmaf(Rv, S, -1.0f);
        fg[j] = __builtin_fmaf(Gv, S, -1.0f);
        fb[j] = __builtin_fmaf(Bv, S, -1.0f);
    }
    *reinterpret_cast<float4*>(o)                 = make_float4(fr[0], fr[1], fr[2], fr[3]);
    *reinterpret_cast<float4*>(o + 4)             = make_float4(fr[4], fr[5], fr[6], fr[7]);
    *reinterpret_cast<float4*>(o + plane)         = make_float4(fg[0], fg[1], fg[2], fg[3]);
    *reinterpret_cast<float4*>(o + plane + 4)     = make_float4(fg[4], fg[5], fg[6], fg[7]);
    *reinterpret_cast<float4*>(o + 2 * plane)     = make_float4(fb[0], fb[1], fb[2], fb[3]);
    *reinterpret_cast<float4*>(o + 2 * plane + 4) = make_float4(fb[4], fb[5], fb[6], fb[7]);
}

__global__ __launch_bounds__(256, 4) void jpeg_k(const float* __restrict__ img,
                                                 const float* __restrict__ QY,
                                                 const float* __restrict__ QC,
                                                 float* __restrict__ out) {
    __shared__ float lds_q[2][64];
    __shared__ float lds_rq[2][64];
    {
        const int tt = threadIdx.x;
        if (tt < 128) {
            const int cc = tt >> 6, idx = tt & 63;
            const float q = (cc ? QC : QY)[idx];
            lds_q[cc][idx]  = q;
            lds_rq[cc][idx] = divf(1.0f, q);   // exact RN(1/q), once per block
        }
    }
    __syncthreads();

    const int lane = threadIdx.x & 63;
    const int g  = lane >> 3;
    const int wv = threadIdx.x >> 6;
    const size_t plane = 1048576;  // 1024*1024
    const int row = blockIdx.y * 8 + g;
    const int span = blockIdx.x * 8 + wv * 2;            // two 64-col spans/wave
    const size_t zr = (size_t)blockIdx.z * (3 * plane) + (size_t)row * 1024;
    const size_t base0 = zr + (size_t)span * 64 + (lane & 7) * 8;
    const size_t base1 = base0 + 64;

    // Two independent sets: t[s*3+c] — 6 pipelines of ILP per thread.
    float t[6][8];
    color_in(img + base0, plane, t[0], t[1], t[2]);
    color_in(img + base1, plane, t[3], t[4], t[5]);

    // ---- Stage 1 (x6): tmp[i, k=g]
#pragma unroll
    for (int p = 0; p < 6; ++p) fwd8(t[p]);
    transpose6(t, g);    // row layout: t[p][k] = tmp_p[i=g, k]
    // ---- Stage 2 (x6): z[g, l]
#pragma unroll
    for (int p = 0; p < 6; ++p) fwd8(t[p]);

    // Band-hedged quantization (band >> any accumulation-order delta).
#pragma unroll
    for (int p = 0; p < 6; ++p) {
        const int qi = ((p % 3) == 0) ? 0 : 1;
        const float* qp  = &lds_q[qi][g * 8];
        const float* rqp = &lds_rq[qi][g * 8];
#pragma unroll
        for (int l = 0; l < 8; ++l) {
            const float q  = qp[l];
            const float tq = mulf(t[p][l], rqp[l]);
            const float r  = rintf(tq);
            const float d  = subf(tq, r);
            const float dist = fabsf(fabsf(d) - 0.5f);
            const float eps = __builtin_fmaf(fabsf(tq), 8e-6f, 1.5e-5f);
            t[p][l] = (dist < eps) ? mulf(addf(r, copysignf(0.5f, d)), q)
                                   : mulf(r, q);
        }
    }

    // IDCT + transpose-back, from row layout t[p][l] = Zq[g][l]:
    //   inv -> (Zq D)[g][n];  T -> (Zq D)[j][g];
    //   inv -> (Dt Zq D)[a][g] = rec_x[a][g] = out_P[g][a].   (store-ready)
#pragma unroll
    for (int p = 0; p < 6; ++p) inv8f(t[p]);
    transpose6(t, g);
#pragma unroll
    for (int p = 0; p < 6; ++p) inv8f(t[p]);

    color_out(out + base0, plane, t[0], t[1], t[2]);
    color_out(out + base1, plane, t[3], t[4], t[5]);
}

extern "C" void kernel_launch(void* const* d_in, const int* in_sizes, int n_in,
                              void* d_out, int out_size, void* d_ws, size_t ws_size,
                              hipStream_t stream) {
    const float* img = (const float*)d_in[0];
    const float* QY  = (const float*)d_in[1];
    const float* QC  = (const float*)d_in[2];
    float* out = (float*)d_out;
    const int B = in_sizes[0] / (3 * 1024 * 1024);
    dim3 grid(1024 / 512, 1024 / 8, B);
    jpeg_k<<<grid, dim3(256), 0, stream>>>(img, QY, QC, out);
}

// Round 20
// 46.565 us; speedup vs baseline: 1.0491x; 1.0491x over previous
//
#include <hip/hip_runtime.h>

// ---- f64 DCT magnitudes (0.5*cos(m*pi/16)); f32 casts match np.asarray(D,f32).
#define C0 0.35355339059327373
#define C1 0.49039264020161522
#define C2 0.46193976625564337
#define C3 0.41573480615127262
#define C5 0.27778511650980109
#define C6 0.19134171618254489
#define C7 0.09754516100806413

#define F0 ((float)C0)
#define F1 ((float)C1)
#define F2 ((float)C2)
#define F3 ((float)C3)
#define F5 ((float)C5)
#define F6 ((float)C6)
#define F7 ((float)C7)

// ---- exact-f32 scalar helpers (boundary-critical paths).
__device__ __forceinline__ float mulf(float a, float b) {
#pragma clang fp contract(off)
    return a * b;
}
__device__ __forceinline__ float addf(float a, float b) {
#pragma clang fp contract(off)
    return a + b;
}
__device__ __forceinline__ float subf(float a, float b) {
#pragma clang fp contract(off)
    return a - b;
}
__device__ __forceinline__ float divf(float a, float b) {
#pragma clang fp contract(off)
    return a / b;
}

// ---- forward DCT-II butterfly: m[i] <- sum_n D[i][n]*m[n]. Accumulation
// order differs from ref's chain by <= ~10 ulps -> covered by the hedge band.
__device__ __forceinline__ void fwd8(float m[8]) {
    const float e0 = m[0] + m[7], e1 = m[1] + m[6], e2 = m[2] + m[5], e3 = m[3] + m[4];
    const float o0 = m[0] - m[7], o1 = m[1] - m[6], o2 = m[2] - m[5], o3 = m[3] - m[4];
    m[0] = F0 * (e0 + e1 + e2 + e3);
    m[4] = F0 * (e0 - e1 - e2 + e3);
    m[2] = F2*e0 + F6*e1 - F6*e2 - F2*e3;
    m[6] = F6*e0 - F2*e1 + F2*e2 - F6*e3;
    m[1] = F1*o0 + F3*o1 + F5*o2 + F7*o3;
    m[3] = F3*o0 - F7*o1 - F1*o2 - F5*o3;
    m[5] = F5*o0 - F1*o1 + F7*o2 + F3*o3;
    m[7] = F7*o0 - F5*o1 + F3*o2 - F1*o3;
}

// ---- fast f32 IDCT butterfly: out[n] = sum_u D[u][n]*in[u]. Precision
// non-critical (affects only +-1-level final pixel rounding = 0.0078).
__device__ __forceinline__ void inv8f(float m[8]) {
    const float a0 = F0*m[0] + F2*m[2] + F0*m[4] + F6*m[6];
    const float a1 = F0*m[0] + F6*m[2] - F0*m[4] - F2*m[6];
    const float a2 = F0*m[0] - F6*m[2] - F0*m[4] + F2*m[6];
    const float a3 = F0*m[0] - F2*m[2] + F0*m[4] - F6*m[6];
    const float o0 = F1*m[1] + F3*m[3] + F5*m[5] + F7*m[7];
    const float o1 = F3*m[1] - F7*m[3] - F1*m[5] - F5*m[7];
    const float o2 = F5*m[1] - F1*m[3] + F7*m[5] + F3*m[7];
    const float o3 = F7*m[1] - F5*m[3] + F3*m[5] - F1*m[7];
    m[0] = a0 + o0; m[7] = a0 - o0;
    m[1] = a1 + o1; m[6] = a1 - o1;
    m[2] = a2 + o2; m[5] = a2 - o2;
    m[3] = a3 + o3; m[4] = a3 - o3;
}

__device__ __forceinline__ float dpp_xor8(float x) {
    // DPP row_ror:8 on 16-lane rows == lane ^ 8 (pure VALU, no lgkmcnt).
    return __builtin_bit_cast(float,
        __builtin_amdgcn_mov_dpp(__builtin_bit_cast(int, x), 0x128, 0xf, 0xf, true));
}

// 8x8 transpose of ALL THREE channels, stage-interleaved for cross-channel ILP.
//   stage xor8  : DPP row_ror:8 + selects (VALU)
//   stage xor16 : v_permlane16_swap (1 op per register pair, both outputs)
//   stage xor32 : v_permlane32_swap
__device__ __forceinline__ void transpose3(float m[3][8], int g) {
    const bool up1 = (g & 1) != 0;
#pragma unroll
    for (int c = 0; c < 3; ++c) {
#pragma unroll
        for (int j = 0; j < 8; j += 2) {
            const int jj = j | 1;
            const float yj  = dpp_xor8(m[c][j]);
            const float yjj = dpp_xor8(m[c][jj]);
            m[c][j]  = up1 ? yjj : m[c][j];
            m[c][jj] = up1 ? m[c][jj] : yj;
        }
    }
#pragma unroll
    for (int c = 0; c < 3; ++c) {
#pragma unroll
        for (int j = 0; j < 8; ++j) {
            if ((j & 2) == 0) {
                const int jj = j | 2;
                asm("v_permlane16_swap_b32 %0, %1" : "+v"(m[c][j]), "+v"(m[c][jj]));
            }
        }
    }
#pragma unroll
    for (int c = 0; c < 3; ++c) {
#pragma unroll
        for (int j = 0; j < 4; ++j) {
            const int jj = j | 4;
            asm("v_permlane32_swap_b32 %0, %1" : "+v"(m[c][j]), "+v"(m[c][jj]));
        }
    }
}

__global__ __launch_bounds__(256, 4) void jpeg_k(const float* __restrict__ img,
                                                 const float* __restrict__ QY,
                                                 const float* __restrict__ QC,
                                                 float* __restrict__ out) {
    __shared__ float lds_q[2][64];
    __shared__ float lds_rq[2][64];
    {
        const int t = threadIdx.x;
        if (t < 128) {
            const int cc = t >> 6, idx = t & 63;
            const float q = (cc ? QC : QY)[idx];
            lds_q[cc][idx]  = q;
            lds_rq[cc][idx] = divf(1.0f, q);   // exact RN(1/q), once per block
        }
    }
    __syncthreads();

    const int lane = threadIdx.x & 63;
    const int g  = lane >> 3;
    const int wv = threadIdx.x >> 6;
    const size_t plane = 1048576;  // 1024*1024
    const int row = blockIdx.y * 8 + g;
    const int col = (blockIdx.x * 4 + wv) * 64 + (lane & 7) * 8;
    const size_t base = (size_t)blockIdx.z * (3 * plane) + (size_t)row * 1024 + (size_t)col;

    const float* pR = img + base;
    const float4 r0 = *reinterpret_cast<const float4*>(pR);
    const float4 r1 = *reinterpret_cast<const float4*>(pR + 4);
    const float4 g0 = *reinterpret_cast<const float4*>(pR + plane);
    const float4 g1 = *reinterpret_cast<const float4*>(pR + plane + 4);
    const float4 b0 = *reinterpret_cast<const float4*>(pR + 2 * plane);
    const float4 b1 = *reinterpret_cast<const float4*>(pR + 2 * plane + 4);
    const float Rf[8] = {r0.x, r0.y, r0.z, r0.w, r1.x, r1.y, r1.z, r1.w};
    const float Gf[8] = {g0.x, g0.y, g0.z, g0.w, g1.x, g1.y, g1.z, g1.w};
    const float Bf[8] = {b0.x, b0.y, b0.z, b0.w, b1.x, b1.y, b1.z, b1.w};

    // Exact f32 rgb->ycbcr (literal numpy op order, rintf = RNE = np.round).
    // Must be bit-exact: integer Y/Cb/Cr feed the quant boundary decisions.
    // Directly produce centered values t = round(.) - 128 (Sterbenz-exact).
    float t[3][8];
#pragma unroll
    for (int j = 0; j < 8; ++j) {
        const float xr = mulf(addf(mulf(Rf[j], 0.5f), 0.5f), 255.0f);
        const float xg = mulf(addf(mulf(Gf[j], 0.5f), 0.5f), 255.0f);
        const float xb = mulf(addf(mulf(Bf[j], 0.5f), 0.5f), 255.0f);
        const float Yi  = rintf(addf(addf(addf(mulf((float)0.256788, xr), mulf((float)0.504129, xg)),
                                          mulf((float)0.0979059, xb)), 16.0f));
        const float Cbi = rintf(addf(subf(subf(128.0f, mulf((float)0.148224, xr)),
                                          mulf((float)0.290992, xg)), mulf((float)0.439216, xb)));
        const float Cri = rintf(subf(subf(addf(128.0f, mulf((float)0.439216, xr)),
                                          mulf((float)0.367788, xg)), mulf((float)0.0714275, xb)));
        t[0][j] = subf(Yi,  128.0f);
        t[1][j] = subf(Cbi, 128.0f);
        t[2][j] = subf(Cri, 128.0f);
    }

    // ---- Stage 1 (x3 interleaved): tmp[i, k=g]
#pragma unroll
    for (int c = 0; c < 3; ++c) fwd8(t[c]);
    transpose3(t, g);    // row layout: t[c][k] = tmp_c[i=g, k]
    // ---- Stage 2 (x3): z[g, l]
#pragma unroll
    for (int c = 0; c < 3; ++c) fwd8(t[c]);

    // Band-hedged quantization (band >> any accumulation-order delta).
#pragma unroll
    for (int c = 0; c < 3; ++c) {
        const int qi = (c == 0) ? 0 : 1;
        const float* qp  = &lds_q[qi][g * 8];
        const float* rqp = &lds_rq[qi][g * 8];
#pragma unroll
        for (int l = 0; l < 8; ++l) {
            const float q  = qp[l];
            const float tt = mulf(t[c][l], rqp[l]);
            const float r  = rintf(tt);
            const float d  = subf(tt, r);
            const float dist = fabsf(fabsf(d) - 0.5f);
            const float eps = __builtin_fmaf(fabsf(tt), 8e-6f, 1.5e-5f);
            t[c][l] = (dist < eps) ? mulf(addf(r, copysignf(0.5f, d)), q)
                                   : mulf(r, q);
        }
    }

    // IDCT + transpose-back, from row layout t[c][l] = Zq[g][l]:
    //   inv -> (Zq D)[g][n];  T -> (Zq D)[j][g];
    //   inv -> (Dt Zq D)[a][g] = rec_x[a][g] = out_P[g][a].   (store-ready)
#pragma unroll
    for (int c = 0; c < 3; ++c) inv8f(t[c]);
    transpose3(t, g);
#pragma unroll
    for (int c = 0; c < 3; ++c) inv8f(t[c]);

    // Fast final color stage (continuous path: 1e-7-level deviation ok).
    float fr[8], fg[8], fb[8];
    const float S = 2.0f / 255.0f;
#pragma unroll
    for (int j = 0; j < 8; ++j) {
        const float y  = t[0][j] + 112.0f;          // (+128) - 16
        const float cb = t[1][j];                    // (+128) - 128
        const float cr = t[2][j];
        const float Rv = rintf(__builtin_fmaf(1.16438f, y,
                               __builtin_fmaf(1.59603f, cr, 3.01124e-07f * cb)));
        const float Gv = rintf(__builtin_fmaf(1.16438f, y,
                               -__builtin_fmaf(0.391763f, cb, 0.812968f * cr)));
        const float Bv = rintf(__builtin_fmaf(1.16438f, y,
                               __builtin_fmaf(2.01723f, cb, 3.05426e-06f * cr)));
        fr[j] = __builtin_fmaf(Rv, S, -1.0f);
        fg[j] = __builtin_fmaf(Gv, S, -1.0f);
        fb[j] = __builtin_fmaf(Bv, S, -1.0f);
    }

    float* o = out + base;
    *reinterpret_cast<float4*>(o)                 = make_float4(fr[0], fr[1], fr[2], fr[3]);
    *reinterpret_cast<float4*>(o + 4)             = make_float4(fr[4], fr[5], fr[6], fr[7]);
    *reinterpret_cast<float4*>(o + plane)         = make_float4(fg[0], fg[1], fg[2], fg[3]);
    *reinterpret_cast<float4*>(o + plane + 4)     = make_float4(fg[4], fg[5], fg[6], fg[7]);
    *reinterpret_cast<float4*>(o + 2 * plane)     = make_float4(fb[0], fb[1], fb[2], fb[3]);
    *reinterpret_cast<float4*>(o + 2 * plane + 4) = make_float4(fb[4], fb[5], fb[6], fb[7]);
}

extern "C" void kernel_launch(void* const* d_in, const int* in_sizes, int n_in,
                              void* d_out, int out_size, void* d_ws, size_t ws_size,
                              hipStream_t stream) {
    const float* img = (const float*)d_in[0];
    const float* QY  = (const float*)d_in[1];
    const float* QC  = (const float*)d_in[2];
    float* out = (float*)d_out;
    const int B = in_sizes[0] / (3 * 1024 * 1024);
    dim3 grid(1024 / 256, 1024 / 8, B);
    jpeg_k<<<grid, dim3(256), 0, stream>>>(img, QY, QC, out);
}